// Round 11
// baseline (58.267 us; speedup 1.0000x reference)
//
#include <hip/hip_runtime.h>

// B=64, IDF=128, CDF=256, L=256, S2=1024.
// Four kernels (split along roofline lines, all DMA-staged):
//   k_tcvt_all : W -> W^T + W fp16 ; ctx -> ctx^T + ctx fp16
//   k_g1   : M = wc(f32->fp16) @ W^T fp16   [8192x256]  64x64, 4 blk/CU
//   k_mid  : logits = M @ ctx^T -> softmax -> out2 = P^T, Yt = P @ ctx^T'
//   k_out1 : out1 = Yt @ W^T'               [8192x1024] 128x128, 2 blk/CU

typedef unsigned short u16;
typedef _Float16 f16;
typedef __attribute__((ext_vector_type(8))) _Float16 f16x8;    // 4 VGPRs
typedef __attribute__((ext_vector_type(4))) float f32x4;       // MFMA acc
typedef __attribute__((ext_vector_type(4))) unsigned int u32x4;

#define MFMA_F16(a, b, c) __builtin_amdgcn_mfma_f32_16x16x32_f16((a), (b), (c), 0, 0, 0)

__device__ __forceinline__ u16 f2h(float v) {
    f16 h = (f16)v;                      // v_cvt_f16_f32, RNE
    return __builtin_bit_cast(u16, h);
}
__device__ __forceinline__ float h2f(u16 h) {
    return (float)__builtin_bit_cast(f16, h);
}
__device__ __forceinline__ unsigned pk2h(float a, float b) {
    return (unsigned)f2h(a) | ((unsigned)f2h(b) << 16);
}
__device__ __forceinline__ int xcd_swz(int bid, int nwg) {
    return (bid & 7) * (nwg >> 3) + (bid >> 3);
}
// async global->LDS, 16 B/lane; LDS dest = wave-uniform base + lane*16
__device__ __forceinline__ void gload16(const u16* g, u16* l) {
    __builtin_amdgcn_global_load_lds(
        (__attribute__((address_space(1))) void*)(u16*)g,
        (__attribute__((address_space(3))) void*)l, 16, 0, 0);
}

// ---------------------------------------------------------------------------
// Converts: z<64 -> ctx mat z: CtP (plain fp16) + CtH (transposed fp16);
//           z>=64 -> W band: Wp (plain fp16) + WtH (transposed fp16).
__global__ void k_tcvt_all(const float* __restrict__ Wsrc,
                           const float* __restrict__ ctx,
                           u16* __restrict__ WtH, u16* __restrict__ Wp,
                           u16* __restrict__ CtH, u16* __restrict__ CtP) {
    __shared__ float tile[32][33];
    const int z = blockIdx.z;
    const int tx = threadIdx.x & 31, ty0 = threadIdx.x >> 5;   // 32 x 8
    if (z < 64) {
        const float* s = ctx + (size_t)z * 65536;
        const int c0 = blockIdx.x * 32, r0 = blockIdx.y * 32;
#pragma unroll
        for (int i = 0; i < 4; i++) {
            int ty = ty0 + i * 8;
            float v = s[(size_t)(r0 + ty) * 256 + c0 + tx];
            tile[ty][tx] = v;
            CtP[(size_t)z * 65536 + (size_t)(r0 + ty) * 256 + c0 + tx] = f2h(v);
        }
        __syncthreads();
#pragma unroll
        for (int i = 0; i < 4; i++) {
            int ty = ty0 + i * 8;
            CtH[(size_t)z * 65536 + (size_t)(c0 + ty) * 256 + r0 + tx] = f2h(tile[tx][ty]);
        }
    } else {
        const int r0 = (z - 64) * 256 + blockIdx.y * 32;       // W rows
        const int c0 = blockIdx.x * 32;
#pragma unroll
        for (int i = 0; i < 4; i++) {
            int ty = ty0 + i * 8;
            float v = Wsrc[(size_t)(r0 + ty) * 256 + c0 + tx];
            tile[ty][tx] = v;
            Wp[(size_t)(r0 + ty) * 256 + c0 + tx] = f2h(v);
        }
        __syncthreads();
#pragma unroll
        for (int i = 0; i < 4; i++) {
            int ty = ty0 + i * 8;
            WtH[(size_t)(c0 + ty) * 1024 + r0 + tx] = f2h(tile[tx][ty]);
        }
    }
}

// ---------------------------------------------------------------------------
// G1: M = wc @ WtH^T.  64x64 tile, BK=64, 512 thr (8 waves 2m x 4n, 32x16).
// A = wc f32 reg-staged + converted; B = WtH via global_load_lds (swizzled src).
// LDS 32 KB -> up to 4 blocks/CU. Grid 512.
__global__ __launch_bounds__(512, 4) void k_g1(
    const float* __restrict__ wc, const u16* __restrict__ WtH,
    u16* __restrict__ MH)
{
    __shared__ __align__(16) u16 As[2][64 * 64];
    __shared__ __align__(16) u16 Bs[2][64 * 64];

    const int sbl = xcd_swz((int)blockIdx.x, (int)gridDim.x);
    const int bx = sbl & 3, by = sbl >> 2;
    const int m0 = by * 64, n0 = bx * 64;

    const int t = threadIdx.x;
    const int w = t >> 6, g = (t >> 4) & 3, r = t & 15;
    const int mB = (w >> 2) * 32, nB = (w & 3) * 16;

    float4 fa[2];
    auto LOADA = [&](int c) {
#pragma unroll
        for (int i = 0; i < 2; i++)
            fa[i] = *((const float4*)(wc + (size_t)(m0 + i * 32 + (t >> 4)) * 1024 + c * 64) + (t & 15));
    };
    auto STOREA = [&](int bi) {
        const int grp = (t & 15) >> 1, half = t & 1;
#pragma unroll
        for (int i = 0; i < 2; i++) {
            const int row = i * 32 + (t >> 4);
            uint2 d = make_uint2(pk2h(fa[i].x, fa[i].y), pk2h(fa[i].z, fa[i].w));
            *(uint2*)&As[bi][row * 64 + ((grp ^ (row & 7)) << 3) + (half << 2)] = d;
        }
    };
    auto ISSUEB = [&](int c, int bi) {
        const int row = t >> 3;
        const u16* gp = WtH + (size_t)(n0 + row) * 1024 + c * 64 + (((t & 7) ^ (row & 7)) << 3);
        gload16(gp, &Bs[bi][(w * 8) * 64]);
    };

    f32x4 acc[2] = {};
    LOADA(0); STOREA(0); LOADA(1);
    ISSUEB(0, 0);
    __syncthreads();

#pragma unroll 1
    for (int c = 0; c < 16; ++c) {
        if (c + 1 < 16) ISSUEB(c + 1, (c + 1) & 1);
#pragma unroll
        for (int kh = 0; kh < 2; kh++) {
            f16x8 aF[2], bF;
#pragma unroll
            for (int mi = 0; mi < 2; mi++) {
                const int row = mB + 16 * mi + r;
                aF[mi] = *(const f16x8*)&As[c & 1][row * 64 + ((((kh << 2) | g) ^ (row & 7)) << 3)];
            }
            {
                const int row = nB + r;
                bF = *(const f16x8*)&Bs[c & 1][row * 64 + ((((kh << 2) | g) ^ (row & 7)) << 3)];
            }
#pragma unroll
            for (int mi = 0; mi < 2; mi++)
                acc[mi] = MFMA_F16(aF[mi], bF, acc[mi]);
        }
        if (c + 1 < 16) { STOREA((c + 1) & 1); if (c + 2 < 16) LOADA(c + 2); }
        __syncthreads();
    }

#pragma unroll
    for (int mi = 0; mi < 2; mi++)
#pragma unroll
        for (int rr = 0; rr < 4; rr++) {
            const int row = m0 + mB + 16 * mi + 4 * g + rr;
            MH[(size_t)row * 256 + n0 + nB + r] = f2h(acc[mi][rr]);
        }
}

// ---------------------------------------------------------------------------
// MID: per (b, 32-row band): logits (4 CtH chunks) -> softmax -> out2 = P^T,
// PV (4 CtP chunks) -> Yt (fp16, global). 256 blocks x 512 thr.
__global__ __launch_bounds__(512, 2) void k_mid(
    const u16* __restrict__ MH, const u16* __restrict__ CtH,
    const u16* __restrict__ CtP, u16* __restrict__ YtH,
    float* __restrict__ out2)
{
    __shared__ __align__(16) u16 smA[32 * 256];      // 16 KB
    __shared__ __align__(16) u16 smB[2][256 * 64];   // 64 KB
    __shared__ float red[32][8];

    const int sbl = xcd_swz((int)blockIdx.x, (int)gridDim.x);
    const int b = sbl >> 2;
    const int m0 = (sbl & 3) * 32;
    const int gi0 = b * 128 + m0;
    const int t = threadIdx.x;
    const int w = t >> 6, g = (t >> 4) & 3, r = t & 15;

    // stage MH rows gi0..gi0+31 into smA (swizzled), 2 passes
#pragma unroll
    for (int i = 0; i < 2; i++) {
        const int row = i * 16 + (t >> 5), grp = t & 31;
        u32x4 v = *(const u32x4*)(MH + (size_t)(gi0 + row) * 256 + grp * 8);
        *(u32x4*)&smA[row * 256 + ((grp ^ (row & 7)) << 3)] = v;
    }

    const u16* Bh = CtH + (size_t)b * 65536;
    const u16* Bp = CtP + (size_t)b * 65536;

    auto ISSUE = [&](const u16* base, int c, int bi) {
#pragma unroll
        for (int j = 0; j < 4; j++) {
            const int row = j * 64 + (t >> 3);
            const u16* gp = base + (size_t)row * 256 + c * 64 + (((t & 7) ^ (row & 7)) << 3);
            gload16(gp, &smB[bi][(j * 64 + w * 8) * 64]);
        }
    };

    ISSUE(Bh, 0, 0);
    __syncthreads();

    // ---- logits
    f32x4 accL[2][2] = {};
#pragma unroll
    for (int lc = 0; lc < 4; ++lc) {
        if (lc < 3) ISSUE(Bh, lc + 1, (lc + 1) & 1);
        else        ISSUE(Bp, 0, (lc + 1) & 1);
#pragma unroll
        for (int kh = 0; kh < 2; kh++) {
            const int grp = lc * 8 + kh * 4 + g;
            f16x8 aF[2], bF[2];
#pragma unroll
            for (int mi = 0; mi < 2; mi++)
                aF[mi] = *(const f16x8*)&smA[(mi * 16 + r) * 256 + ((grp ^ (r & 7)) << 3)];
#pragma unroll
            for (int ni = 0; ni < 2; ni++) {
                const int row = w * 32 + ni * 16 + r;
                bF[ni] = *(const f16x8*)&smB[lc & 1][row * 64 + ((((kh << 2) | g) ^ (row & 7)) << 3)];
            }
#pragma unroll
            for (int mi = 0; mi < 2; mi++)
#pragma unroll
                for (int ni = 0; ni < 2; ni++)
                    accL[mi][ni] = MFMA_F16(aF[mi], bF[ni], accL[mi][ni]);
        }
        __syncthreads();
    }

    // ---- softmax over 256 cols (8 waves share rows via red[32][8])
    float s_[2][4];
#pragma unroll
    for (int mi = 0; mi < 2; mi++)
#pragma unroll
        for (int rr = 0; rr < 4; rr++) {
            float mx = fmaxf(accL[mi][0][rr], accL[mi][1][rr]);
#pragma unroll
            for (int m = 1; m < 16; m <<= 1) mx = fmaxf(mx, __shfl_xor(mx, m));
            if (r == 0) red[mi * 16 + 4 * g + rr][w] = mx;
        }
    __syncthreads();
#pragma unroll
    for (int mi = 0; mi < 2; mi++)
#pragma unroll
        for (int rr = 0; rr < 4; rr++) {
            const int lrow = mi * 16 + 4 * g + rr;
            float gmx = red[lrow][0];
#pragma unroll
            for (int j = 1; j < 8; j++) gmx = fmaxf(gmx, red[lrow][j]);
            float s = 0.f;
#pragma unroll
            for (int ni = 0; ni < 2; ni++) {
                float e = __expf(accL[mi][ni][rr] - gmx);
                accL[mi][ni][rr] = e;
                s += e;
            }
#pragma unroll
            for (int m = 1; m < 16; m <<= 1) s += __shfl_xor(s, m);
            s_[mi][rr] = s;
        }
    __syncthreads();
#pragma unroll
    for (int mi = 0; mi < 2; mi++)
#pragma unroll
        for (int rr = 0; rr < 4; rr++)
            if (r == 0) red[mi * 16 + 4 * g + rr][w] = s_[mi][rr];
    __syncthreads();

    // ---- normalize + park P into smA (M dead)
#pragma unroll
    for (int mi = 0; mi < 2; mi++)
#pragma unroll
        for (int rr = 0; rr < 4; rr++) {
            const int lrow = mi * 16 + 4 * g + rr;
            float sum = red[lrow][0];
#pragma unroll
            for (int j = 1; j < 8; j++) sum += red[lrow][j];
            const float inv = 1.f / sum;
#pragma unroll
            for (int ni = 0; ni < 2; ni++) {
                const float v = accL[mi][ni][rr] * inv;
                const int col = w * 32 + ni * 16 + r;
                smA[lrow * 256 + (((col >> 3) ^ (lrow & 7)) << 3) + (col & 7)] = f2h(v);
            }
        }
    __syncthreads();

    // ---- out2 = P^T: thread t<256 owns column l, 128 B contiguous f32 run
    if (t < 256) {
        const int l = t;
        float vals[32];
#pragma unroll
        for (int row = 0; row < 32; row++)
            vals[row] = h2f(smA[row * 256 + (((l >> 3) ^ (row & 7)) << 3) + (l & 7)]);
        float4* dst = (float4*)(out2 + (size_t)b * 32768 + (size_t)l * 128 + m0);
#pragma unroll
        for (int q = 0; q < 8; q++)
            dst[q] = make_float4(vals[4 * q], vals[4 * q + 1],
                                 vals[4 * q + 2], vals[4 * q + 3]);
    }

    // ---- PV: Yt[i][c] = sum_l P[i][l] * ctx[c][l]
    f32x4 accP[2][2] = {};
#pragma unroll
    for (int pc = 0; pc < 4; ++pc) {
        if (pc < 3) ISSUE(Bp, pc + 1, (pc + 1) & 1);
#pragma unroll
        for (int kh = 0; kh < 2; kh++) {
            const int grp = pc * 8 + kh * 4 + g;
            f16x8 aF[2], bF[2];
#pragma unroll
            for (int mi = 0; mi < 2; mi++)
                aF[mi] = *(const f16x8*)&smA[(mi * 16 + r) * 256 + ((grp ^ (r & 7)) << 3)];
#pragma unroll
            for (int ni = 0; ni < 2; ni++) {
                const int row = w * 32 + ni * 16 + r;
                bF[ni] = *(const f16x8*)&smB[pc & 1][row * 64 + ((((kh << 2) | g) ^ (row & 7)) << 3)];
            }
#pragma unroll
            for (int mi = 0; mi < 2; mi++)
#pragma unroll
                for (int ni = 0; ni < 2; ni++)
                    accP[mi][ni] = MFMA_F16(aF[mi], bF[ni], accP[mi][ni]);
        }
        __syncthreads();
    }

    // ---- Yt epilogue (fp16 global)
#pragma unroll
    for (int mi = 0; mi < 2; mi++)
#pragma unroll
        for (int ni = 0; ni < 2; ni++)
#pragma unroll
            for (int rr = 0; rr < 4; rr++) {
                const int row = gi0 + mi * 16 + 4 * g + rr;
                const int col = w * 32 + ni * 16 + r;
                YtH[(size_t)row * 256 + col] = f2h(accP[mi][ni][rr]);
            }
}

// ---------------------------------------------------------------------------
// OUT1: out1 = Yt @ Wp^T. M=8192, N=1024, K=256. 128x128 tile, BK=64,
// 512 thr (8 waves 2m x 4n, wave 64x32). Both operands via global_load_lds.
// Grid 512 (64 x 8), LDS 64 KB -> 2 blocks/CU.
__global__ __launch_bounds__(512, 4) void k_out1(
    const u16* __restrict__ Yt, const u16* __restrict__ Wp,
    float* __restrict__ out1)
{
    __shared__ __align__(16) u16 As[2][128 * 64];
    __shared__ __align__(16) u16 Bs[2][128 * 64];

    const int sbl = xcd_swz((int)blockIdx.x, (int)gridDim.x);
    const int bx = sbl & 7, by = sbl >> 3;
    const int m0 = by * 128, n0 = bx * 128;

    const int t = threadIdx.x;
    const int w = t >> 6, g = (t >> 4) & 3, r = t & 15;
    const int mB = (w >> 2) * 64, nB = (w & 3) * 32;

    auto ISSUE = [&](int c, int bi) {
#pragma unroll
        for (int j = 0; j < 2; j++) {
            const int row = j * 64 + (t >> 3);
            const u16* gp = Yt + (size_t)(m0 + row) * 256 + c * 64 + (((t & 7) ^ (row & 7)) << 3);
            gload16(gp, &As[bi][(j * 64 + w * 8) * 64]);
        }
#pragma unroll
        for (int j = 0; j < 2; j++) {
            const int row = j * 64 + (t >> 3);
            const u16* gp = Wp + (size_t)(n0 + row) * 256 + c * 64 + (((t & 7) ^ (row & 7)) << 3);
            gload16(gp, &Bs[bi][(j * 64 + w * 8) * 64]);
        }
    };

    f32x4 acc[4][2] = {};
    ISSUE(0, 0);
    __syncthreads();

#pragma unroll
    for (int c = 0; c < 4; ++c) {
        if (c + 1 < 4) ISSUE(c + 1, (c + 1) & 1);
#pragma unroll
        for (int kh = 0; kh < 2; kh++) {
            f16x8 aF[4], bF[2];
#pragma unroll
            for (int mi = 0; mi < 4; mi++) {
                const int row = mB + 16 * mi + r;
                aF[mi] = *(const f16x8*)&As[c & 1][row * 64 + ((((kh << 2) | g) ^ (row & 7)) << 3)];
            }
#pragma unroll
            for (int ni = 0; ni < 2; ni++) {
                const int row = nB + 16 * ni + r;
                bF[ni] = *(const f16x8*)&Bs[c & 1][row * 64 + ((((kh << 2) | g) ^ (row & 7)) << 3)];
            }
#pragma unroll
            for (int mi = 0; mi < 4; mi++)
#pragma unroll
                for (int ni = 0; ni < 2; ni++)
                    acc[mi][ni] = MFMA_F16(aF[mi], bF[ni], acc[mi][ni]);
        }
        __syncthreads();
    }

#pragma unroll
    for (int mi = 0; mi < 4; mi++)
#pragma unroll
        for (int ni = 0; ni < 2; ni++)
#pragma unroll
            for (int rr = 0; rr < 4; rr++) {
                const int row = m0 + mB + 16 * mi + 4 * g + rr;
                const int col = n0 + nB + 16 * ni + r;
                out1[(size_t)row * 1024 + col] = acc[mi][ni][rr];
            }
}

// ---------------------------------------------------------------------------
extern "C" void kernel_launch(void* const* d_in, const int* in_sizes, int n_in,
                              void* d_out, int out_size, void* d_ws, size_t ws_size,
                              hipStream_t stream) {
    const int B = 64, IDF = 128, CDF = 256, L = 256, S2 = 1024;
    const float* wc  = (const float*)d_in[0];   // [B, IDF, S2]
    const float* ctx = (const float*)d_in[1];   // [B, CDF, L]
    const float* W   = (const float*)d_in[2];   // [S2, CDF]
    float* out1 = (float*)d_out;                          // [B,IDF,S2]
    float* out2 = (float*)d_out + (size_t)B * IDF * S2;   // [B,L,IDF]

    char* ws = (char*)d_ws;
    size_t off = 0;
    auto alloc = [&](size_t bytes) -> char* {
        char* p = ws + off;
        off += (bytes + 255) & ~(size_t)255;
        return p;
    };
    u16* WtH = (u16*)alloc((size_t)CDF * S2 * 2);        // W^T fp16 [256][1024]
    u16* Wp  = (u16*)alloc((size_t)S2 * CDF * 2);        // W   fp16 [1024][256]
    u16* CtH = (u16*)alloc((size_t)B * L * CDF * 2);     // ctx^T fp16 [B][l][c]
    u16* CtP = (u16*)alloc((size_t)B * CDF * L * 2);     // ctx fp16  [B][c][l]
    u16* MH  = (u16*)alloc((size_t)B * IDF * CDF * 2);   // M fp16 [8192][256]
    u16* YtH = (u16*)alloc((size_t)B * IDF * CDF * 2);   // Yt fp16 [8192][256]
    (void)ws_size; // ~26 MB

    k_tcvt_all<<<dim3(8, 8, 68), 256, 0, stream>>>(W, ctx, WtH, Wp, CtH, CtP);
    k_g1<<<512, 512, 0, stream>>>(wc, WtH, MH);
    k_mid<<<256, 512, 0, stream>>>(MH, CtH, CtP, YtH, out2);
    k_out1<<<512, 512, 0, stream>>>(YtH, Wp, out1);
}

// Round 12
// 54.576 us; speedup vs baseline: 1.0676x; 1.0676x over previous
//
#include <hip/hip_runtime.h>

// B=64, IDF=128, CDF=256, L=256, S2=1024.
// Four kernels, all GEMMs use depth-2 REGISTER prefetch (loads for chunk c+2
// issued at iter c; consumed by LDS-store at end of iter c+1 -> latency fully
// hidden by compiler-counted vmcnt, no barrier drain of in-flight loads):
//   k_tcvt_all : W -> W^T + W fp16 ; ctx -> ctx^T + ctx fp16
//   k_g1   : M = wc(f32->fp16) @ W^T fp16   [8192x256]  64x64
//   k_mid  : logits = M @ ctx^T -> softmax -> out2 = P^T, Yt = P @ ctx^T'
//   k_out1 : out1 = Yt @ W^T'               [8192x1024] 128x128

typedef unsigned short u16;
typedef _Float16 f16;
typedef __attribute__((ext_vector_type(8))) _Float16 f16x8;    // 4 VGPRs
typedef __attribute__((ext_vector_type(4))) float f32x4;       // MFMA acc
typedef __attribute__((ext_vector_type(4))) unsigned int u32x4;

#define MFMA_F16(a, b, c) __builtin_amdgcn_mfma_f32_16x16x32_f16((a), (b), (c), 0, 0, 0)

__device__ __forceinline__ u16 f2h(float v) {
    f16 h = (f16)v;                      // v_cvt_f16_f32, RNE
    return __builtin_bit_cast(u16, h);
}
__device__ __forceinline__ float h2f(u16 h) {
    return (float)__builtin_bit_cast(f16, h);
}
__device__ __forceinline__ unsigned pk2h(float a, float b) {
    return (unsigned)f2h(a) | ((unsigned)f2h(b) << 16);
}
__device__ __forceinline__ int xcd_swz(int bid, int nwg) {
    return (bid & 7) * (nwg >> 3) + (bid >> 3);
}

// ---------------------------------------------------------------------------
// Converts: z<64 -> ctx mat z: CtP (plain fp16) + CtH (transposed fp16);
//           z>=64 -> W band: Wp (plain fp16) + WtH (transposed fp16).
__global__ void k_tcvt_all(const float* __restrict__ Wsrc,
                           const float* __restrict__ ctx,
                           u16* __restrict__ WtH, u16* __restrict__ Wp,
                           u16* __restrict__ CtH, u16* __restrict__ CtP) {
    __shared__ float tile[32][33];
    const int z = blockIdx.z;
    const int tx = threadIdx.x & 31, ty0 = threadIdx.x >> 5;   // 32 x 8
    if (z < 64) {
        const float* s = ctx + (size_t)z * 65536;
        const int c0 = blockIdx.x * 32, r0 = blockIdx.y * 32;
#pragma unroll
        for (int i = 0; i < 4; i++) {
            int ty = ty0 + i * 8;
            float v = s[(size_t)(r0 + ty) * 256 + c0 + tx];
            tile[ty][tx] = v;
            CtP[(size_t)z * 65536 + (size_t)(r0 + ty) * 256 + c0 + tx] = f2h(v);
        }
        __syncthreads();
#pragma unroll
        for (int i = 0; i < 4; i++) {
            int ty = ty0 + i * 8;
            CtH[(size_t)z * 65536 + (size_t)(c0 + ty) * 256 + r0 + tx] = f2h(tile[tx][ty]);
        }
    } else {
        const int r0 = (z - 64) * 256 + blockIdx.y * 32;       // W rows
        const int c0 = blockIdx.x * 32;
#pragma unroll
        for (int i = 0; i < 4; i++) {
            int ty = ty0 + i * 8;
            float v = Wsrc[(size_t)(r0 + ty) * 256 + c0 + tx];
            tile[ty][tx] = v;
            Wp[(size_t)(r0 + ty) * 256 + c0 + tx] = f2h(v);
        }
        __syncthreads();
#pragma unroll
        for (int i = 0; i < 4; i++) {
            int ty = ty0 + i * 8;
            WtH[(size_t)(c0 + ty) * 1024 + r0 + tx] = f2h(tile[tx][ty]);
        }
    }
}

// ---------------------------------------------------------------------------
// G1: M = wc @ WtH^T.  64x64 tile, BK=64, 512 thr (8 waves 2m x 4n, 32x16).
// Depth-2 reg prefetch, dbuf swizzled LDS. Grid 512 (2 blocks/CU).
__global__ __launch_bounds__(512, 4) void k_g1(
    const float* __restrict__ wc, const u16* __restrict__ WtH,
    u16* __restrict__ MH)
{
    __shared__ __align__(16) u16 As[2][64 * 64];
    __shared__ __align__(16) u16 Bs[2][64 * 64];

    const int sbl = xcd_swz((int)blockIdx.x, (int)gridDim.x);
    const int bx = sbl & 3, by = sbl >> 2;
    const int m0 = by * 64, n0 = bx * 64;

    const int t = threadIdx.x;
    const int w = t >> 6, g = (t >> 4) & 3, r = t & 15;
    const int mB = (w >> 2) * 32, nB = (w & 3) * 16;

    float4 fa[2][2];                     // [bank][rowband]
    u32x4 ub[2];                         // [bank]

    auto LOADg = [&](int c, int bk) {
#pragma unroll
        for (int i = 0; i < 2; i++)
            fa[bk][i] = *((const float4*)(wc + (size_t)(m0 + i * 32 + (t >> 4)) * 1024 + c * 64) + (t & 15));
        ub[bk] = *((const u32x4*)(WtH + (size_t)(n0 + (t >> 3)) * 1024 + c * 64) + (t & 7));
    };
    auto STOREg = [&](int bk, int bi) {
        const int grpA = (t & 15) >> 1, half = t & 1;
#pragma unroll
        for (int i = 0; i < 2; i++) {
            const int row = i * 32 + (t >> 4);
            uint2 d = make_uint2(pk2h(fa[bk][i].x, fa[bk][i].y), pk2h(fa[bk][i].z, fa[bk][i].w));
            *(uint2*)&As[bi][row * 64 + ((grpA ^ (row & 7)) << 3) + (half << 2)] = d;
        }
        const int rowB = t >> 3, grpB = t & 7;
        *(u32x4*)&Bs[bi][rowB * 64 + ((grpB ^ (rowB & 7)) << 3)] = ub[bk];
    };

    f32x4 acc[2] = {};
    LOADg(0, 0);
    LOADg(1, 1);
    STOREg(0, 0);
    __syncthreads();

#pragma unroll
    for (int c = 0; c < 16; ++c) {
        if (c + 2 < 16) LOADg(c + 2, c & 1);   // bank of dead chunk c
#pragma unroll
        for (int kh = 0; kh < 2; kh++) {
            f16x8 aF[2], bF;
#pragma unroll
            for (int mi = 0; mi < 2; mi++) {
                const int row = mB + 16 * mi + r;
                aF[mi] = *(const f16x8*)&As[c & 1][row * 64 + ((((kh << 2) | g) ^ (row & 7)) << 3)];
            }
            {
                const int row = nB + r;
                bF = *(const f16x8*)&Bs[c & 1][row * 64 + ((((kh << 2) | g) ^ (row & 7)) << 3)];
            }
#pragma unroll
            for (int mi = 0; mi < 2; mi++)
                acc[mi] = MFMA_F16(aF[mi], bF, acc[mi]);
        }
        if (c + 1 < 16) STOREg((c + 1) & 1, (c + 1) & 1);
        __syncthreads();
    }

#pragma unroll
    for (int mi = 0; mi < 2; mi++)
#pragma unroll
        for (int rr = 0; rr < 4; rr++) {
            const int row = m0 + mB + 16 * mi + 4 * g + rr;
            MH[(size_t)row * 256 + n0 + nB + r] = f2h(acc[mi][rr]);
        }
}

// ---------------------------------------------------------------------------
// MID: per (b, 32-row band): 8-chunk stream (CtH 0-3, CtP 4-7), depth-2 reg
// prefetch; softmax + out2 inserted after chunk 3. 256 blocks x 512 thr.
__global__ __launch_bounds__(512, 2) void k_mid(
    const u16* __restrict__ MH, const u16* __restrict__ CtH,
    const u16* __restrict__ CtP, u16* __restrict__ YtH,
    float* __restrict__ out2)
{
    __shared__ __align__(16) u16 smA[32 * 256];      // 16 KB (M -> P)
    __shared__ __align__(16) u16 smB[2][256 * 64];   // 64 KB
    __shared__ float red[32][8];

    const int sbl = xcd_swz((int)blockIdx.x, (int)gridDim.x);
    const int b = sbl >> 2;
    const int m0 = (sbl & 3) * 32;
    const int gi0 = b * 128 + m0;
    const int t = threadIdx.x;
    const int w = t >> 6, g = (t >> 4) & 3, r = t & 15;

    // stage MH rows gi0..gi0+31 into smA (swizzled), 2 passes
#pragma unroll
    for (int i = 0; i < 2; i++) {
        const int row = i * 16 + (t >> 5), grp = t & 31;
        u32x4 v = *(const u32x4*)(MH + (size_t)(gi0 + row) * 256 + grp * 8);
        *(u32x4*)&smA[row * 256 + ((grp ^ (row & 7)) << 3)] = v;
    }

    const u16* Bh = CtH + (size_t)b * 65536;
    const u16* Bp = CtP + (size_t)b * 65536;

    u32x4 ub[2][4];                      // [bank][i]
    auto LOADC = [&](int c, int bk) {
        const u16* base = (c < 4) ? (Bh + c * 64) : (Bp + (c - 4) * 64);
        const int row0 = t >> 3, grp = t & 7;
#pragma unroll
        for (int i = 0; i < 4; i++)
            ub[bk][i] = *((const u32x4*)(base + (size_t)(i * 64 + row0) * 256) + grp);
    };
    auto STOREC = [&](int bk, int bi) {
        const int row0 = t >> 3, grp = t & 7;
#pragma unroll
        for (int i = 0; i < 4; i++) {
            const int row = i * 64 + row0;
            *(u32x4*)&smB[bi][row * 64 + ((grp ^ (row & 7)) << 3)] = ub[bk][i];
        }
    };

    f32x4 accL[2][2] = {};
    f32x4 accP[2][2] = {};

    LOADC(0, 0);
    LOADC(1, 1);
    STOREC(0, 0);
    __syncthreads();

#pragma unroll
    for (int c = 0; c < 8; ++c) {
        if (c + 2 < 8) LOADC(c + 2, c & 1);

#pragma unroll
        for (int kh = 0; kh < 2; kh++) {
            const int kc = c & 3;        // compile-time under unroll
            const int grp = kc * 8 + kh * 4 + g;
            f16x8 aF[2], bF[2];
#pragma unroll
            for (int mi = 0; mi < 2; mi++)
                aF[mi] = *(const f16x8*)&smA[(mi * 16 + r) * 256 + ((grp ^ (r & 7)) << 3)];
#pragma unroll
            for (int ni = 0; ni < 2; ni++) {
                const int row = w * 32 + ni * 16 + r;
                bF[ni] = *(const f16x8*)&smB[c & 1][row * 64 + ((((kh << 2) | g) ^ (row & 7)) << 3)];
            }
            if (c < 4) {
#pragma unroll
                for (int mi = 0; mi < 2; mi++)
#pragma unroll
                    for (int ni = 0; ni < 2; ni++)
                        accL[mi][ni] = MFMA_F16(aF[mi], bF[ni], accL[mi][ni]);
            } else {
#pragma unroll
                for (int mi = 0; mi < 2; mi++)
#pragma unroll
                    for (int ni = 0; ni < 2; ni++)
                        accP[mi][ni] = MFMA_F16(aF[mi], bF[ni], accP[mi][ni]);
            }
        }

        if (c == 3) {
            // ---- softmax over 256 cols (8 waves share rows via red[32][8])
            float s_[2][4];
#pragma unroll
            for (int mi = 0; mi < 2; mi++)
#pragma unroll
                for (int rr = 0; rr < 4; rr++) {
                    float mx = fmaxf(accL[mi][0][rr], accL[mi][1][rr]);
#pragma unroll
                    for (int m = 1; m < 16; m <<= 1) mx = fmaxf(mx, __shfl_xor(mx, m));
                    if (r == 0) red[mi * 16 + 4 * g + rr][w] = mx;
                }
            __syncthreads();
#pragma unroll
            for (int mi = 0; mi < 2; mi++)
#pragma unroll
                for (int rr = 0; rr < 4; rr++) {
                    const int lrow = mi * 16 + 4 * g + rr;
                    float gmx = red[lrow][0];
#pragma unroll
                    for (int j = 1; j < 8; j++) gmx = fmaxf(gmx, red[lrow][j]);
                    float s = 0.f;
#pragma unroll
                    for (int ni = 0; ni < 2; ni++) {
                        float e = __expf(accL[mi][ni][rr] - gmx);
                        accL[mi][ni][rr] = e;
                        s += e;
                    }
#pragma unroll
                    for (int m = 1; m < 16; m <<= 1) s += __shfl_xor(s, m);
                    s_[mi][rr] = s;
                }
            __syncthreads();
#pragma unroll
            for (int mi = 0; mi < 2; mi++)
#pragma unroll
                for (int rr = 0; rr < 4; rr++)
                    if (r == 0) red[mi * 16 + 4 * g + rr][w] = s_[mi][rr];
            __syncthreads();
            // normalize + park P into smA (M dead)
#pragma unroll
            for (int mi = 0; mi < 2; mi++)
#pragma unroll
                for (int rr = 0; rr < 4; rr++) {
                    const int lrow = mi * 16 + 4 * g + rr;
                    float sum = red[lrow][0];
#pragma unroll
                    for (int j = 1; j < 8; j++) sum += red[lrow][j];
                    const float inv = 1.f / sum;
#pragma unroll
                    for (int ni = 0; ni < 2; ni++) {
                        const float v = accL[mi][ni][rr] * inv;
                        const int col = w * 32 + ni * 16 + r;
                        smA[lrow * 256 + (((col >> 3) ^ (lrow & 7)) << 3) + (col & 7)] = f2h(v);
                    }
                }
            __syncthreads();
            // out2 = P^T: thread t<256 owns column l, 128 B contiguous f32 run
            if (t < 256) {
                const int l = t;
                float vals[32];
#pragma unroll
                for (int row = 0; row < 32; row++)
                    vals[row] = h2f(smA[row * 256 + (((l >> 3) ^ (row & 7)) << 3) + (l & 7)]);
                float4* dst = (float4*)(out2 + (size_t)b * 32768 + (size_t)l * 128 + m0);
#pragma unroll
                for (int q = 0; q < 8; q++)
                    dst[q] = make_float4(vals[4 * q], vals[4 * q + 1],
                                         vals[4 * q + 2], vals[4 * q + 3]);
            }
        }

        if (c + 1 < 8) STOREC((c + 1) & 1, (c + 1) & 1);
        __syncthreads();
    }

    // ---- Yt epilogue (fp16 global)
#pragma unroll
    for (int mi = 0; mi < 2; mi++)
#pragma unroll
        for (int ni = 0; ni < 2; ni++)
#pragma unroll
            for (int rr = 0; rr < 4; rr++) {
                const int row = gi0 + mi * 16 + 4 * g + rr;
                const int col = w * 32 + ni * 16 + r;
                YtH[(size_t)row * 256 + col] = f2h(accP[mi][ni][rr]);
            }
}

// ---------------------------------------------------------------------------
// OUT1: out1 = Yt @ Wp^T. 128x128 tile, BK=64, 512 thr (8 waves 2m x 4n,
// wave 64x32), depth-2 reg prefetch, dbuf LDS. Grid 512 (2 blocks/CU).
__global__ __launch_bounds__(512, 4) void k_out1(
    const u16* __restrict__ Yt, const u16* __restrict__ Wp,
    float* __restrict__ out1)
{
    __shared__ __align__(16) u16 As[2][128 * 64];
    __shared__ __align__(16) u16 Bs[2][128 * 64];

    const int sbl = xcd_swz((int)blockIdx.x, (int)gridDim.x);
    const int bx = sbl & 7, by = sbl >> 3;
    const int m0 = by * 128, n0 = bx * 128;

    const int t = threadIdx.x;
    const int w = t >> 6, g = (t >> 4) & 3, r = t & 15;
    const int mB = (w >> 2) * 64, nB = (w & 3) * 32;

    u32x4 ua[2][2], ub[2][2];            // [bank][rowband]
    auto LOADg = [&](int c, int bk) {
        const int row0 = t >> 3, grp = t & 7;
#pragma unroll
        for (int i = 0; i < 2; i++) {
            ua[bk][i] = *((const u32x4*)(Yt + (size_t)(m0 + i * 64 + row0) * 256 + c * 64) + grp);
            ub[bk][i] = *((const u32x4*)(Wp + (size_t)(n0 + i * 64 + row0) * 256 + c * 64) + grp);
        }
    };
    auto STOREg = [&](int bk, int bi) {
        const int row0 = t >> 3, grp = t & 7;
#pragma unroll
        for (int i = 0; i < 2; i++) {
            const int row = i * 64 + row0;
            *(u32x4*)&As[bi][row * 64 + ((grp ^ (row & 7)) << 3)] = ua[bk][i];
            *(u32x4*)&Bs[bi][row * 64 + ((grp ^ (row & 7)) << 3)] = ub[bk][i];
        }
    };

    f32x4 acc[4][2] = {};
    LOADg(0, 0);
    LOADg(1, 1);
    STOREg(0, 0);
    __syncthreads();

#pragma unroll
    for (int c = 0; c < 4; ++c) {
        if (c + 2 < 4) LOADg(c + 2, c & 1);
#pragma unroll
        for (int kh = 0; kh < 2; kh++) {
            f16x8 aF[4], bF[2];
#pragma unroll
            for (int mi = 0; mi < 4; mi++) {
                const int row = mB + 16 * mi + r;
                aF[mi] = *(const f16x8*)&As[c & 1][row * 64 + ((((kh << 2) | g) ^ (row & 7)) << 3)];
            }
#pragma unroll
            for (int ni = 0; ni < 2; ni++) {
                const int row = nB + 16 * ni + r;
                bF[ni] = *(const f16x8*)&Bs[c & 1][row * 64 + ((((kh << 2) | g) ^ (row & 7)) << 3)];
            }
#pragma unroll
            for (int mi = 0; mi < 4; mi++)
#pragma unroll
                for (int ni = 0; ni < 2; ni++)
                    acc[mi][ni] = MFMA_F16(aF[mi], bF[ni], acc[mi][ni]);
        }
        if (c + 1 < 4) STOREg((c + 1) & 1, (c + 1) & 1);
        __syncthreads();
    }

#pragma unroll
    for (int mi = 0; mi < 4; mi++)
#pragma unroll
        for (int ni = 0; ni < 2; ni++)
#pragma unroll
            for (int rr = 0; rr < 4; rr++) {
                const int row = m0 + mB + 16 * mi + 4 * g + rr;
                const int col = n0 + nB + 16 * ni + r;
                out1[(size_t)row * 1024 + col] = acc[mi][ni][rr];
            }
}

// ---------------------------------------------------------------------------
extern "C" void kernel_launch(void* const* d_in, const int* in_sizes, int n_in,
                              void* d_out, int out_size, void* d_ws, size_t ws_size,
                              hipStream_t stream) {
    const int B = 64, IDF = 128, CDF = 256, L = 256, S2 = 1024;
    const float* wc  = (const float*)d_in[0];   // [B, IDF, S2]
    const float* ctx = (const float*)d_in[1];   // [B, CDF, L]
    const float* W   = (const float*)d_in[2];   // [S2, CDF]
    float* out1 = (float*)d_out;                          // [B,IDF,S2]
    float* out2 = (float*)d_out + (size_t)B * IDF * S2;   // [B,L,IDF]

    char* ws = (char*)d_ws;
    size_t off = 0;
    auto alloc = [&](size_t bytes) -> char* {
        char* p = ws + off;
        off += (bytes + 255) & ~(size_t)255;
        return p;
    };
    u16* WtH = (u16*)alloc((size_t)CDF * S2 * 2);        // W^T fp16 [256][1024]
    u16* Wp  = (u16*)alloc((size_t)S2 * CDF * 2);        // W   fp16 [1024][256]
    u16* CtH = (u16*)alloc((size_t)B * L * CDF * 2);     // ctx^T fp16 [B][l][c]
    u16* CtP = (u16*)alloc((size_t)B * CDF * L * 2);     // ctx fp16  [B][c][l]
    u16* MH  = (u16*)alloc((size_t)B * IDF * CDF * 2);   // M fp16 [8192][256]
    u16* YtH = (u16*)alloc((size_t)B * IDF * CDF * 2);   // Yt fp16 [8192][256]
    (void)ws_size; // ~26 MB

    k_tcvt_all<<<dim3(8, 8, 68), 256, 0, stream>>>(W, ctx, WtH, Wp, CtH, CtP);
    k_g1<<<512, 512, 0, stream>>>(wc, WtH, MH);
    k_mid<<<256, 512, 0, stream>>>(MH, CtH, CtP, YtH, out2);
    k_out1<<<512, 512, 0, stream>>>(YtH, Wp, out1);
}

// Round 13
// 54.535 us; speedup vs baseline: 1.0684x; 1.0007x over previous
//
#include <hip/hip_runtime.h>

// B=64, IDF=128, CDF=256, L=256, S2=1024.
// Four kernels, all GEMMs use depth-2 REGISTER prefetch (loads for chunk c+2
// issued at iter c; consumed by LDS-store at end of iter c+1 -> latency fully
// hidden by compiler-counted vmcnt, no barrier drain of in-flight loads):
//   k_tcvt_all : W -> W^T + W fp16 ; ctx -> ctx^T + ctx fp16
//   k_g1   : M = wc(f32->fp16) @ W^T fp16   [8192x256]  64x64
//   k_mid  : logits = M @ ctx^T -> softmax -> out2 = P^T, Yt = P @ ctx^T'
//   k_out1 : out1 = Yt @ W^T'               [8192x1024] 128x128

typedef unsigned short u16;
typedef _Float16 f16;
typedef __attribute__((ext_vector_type(8))) _Float16 f16x8;    // 4 VGPRs
typedef __attribute__((ext_vector_type(4))) float f32x4;       // MFMA acc
typedef __attribute__((ext_vector_type(4))) unsigned int u32x4;

#define MFMA_F16(a, b, c) __builtin_amdgcn_mfma_f32_16x16x32_f16((a), (b), (c), 0, 0, 0)

__device__ __forceinline__ u16 f2h(float v) {
    f16 h = (f16)v;                      // v_cvt_f16_f32, RNE
    return __builtin_bit_cast(u16, h);
}
__device__ __forceinline__ float h2f(u16 h) {
    return (float)__builtin_bit_cast(f16, h);
}
__device__ __forceinline__ unsigned pk2h(float a, float b) {
    return (unsigned)f2h(a) | ((unsigned)f2h(b) << 16);
}
__device__ __forceinline__ int xcd_swz(int bid, int nwg) {
    return (bid & 7) * (nwg >> 3) + (bid >> 3);
}

// ---------------------------------------------------------------------------
// Converts: z<64 -> ctx mat z: CtP (plain fp16) + CtH (transposed fp16);
//           z>=64 -> W band: Wp (plain fp16) + WtH (transposed fp16).
__global__ void k_tcvt_all(const float* __restrict__ Wsrc,
                           const float* __restrict__ ctx,
                           u16* __restrict__ WtH, u16* __restrict__ Wp,
                           u16* __restrict__ CtH, u16* __restrict__ CtP) {
    __shared__ float tile[32][33];
    const int z = blockIdx.z;
    const int tx = threadIdx.x & 31, ty0 = threadIdx.x >> 5;   // 32 x 8
    if (z < 64) {
        const float* s = ctx + (size_t)z * 65536;
        const int c0 = blockIdx.x * 32, r0 = blockIdx.y * 32;
#pragma unroll
        for (int i = 0; i < 4; i++) {
            int ty = ty0 + i * 8;
            float v = s[(size_t)(r0 + ty) * 256 + c0 + tx];
            tile[ty][tx] = v;
            CtP[(size_t)z * 65536 + (size_t)(r0 + ty) * 256 + c0 + tx] = f2h(v);
        }
        __syncthreads();
#pragma unroll
        for (int i = 0; i < 4; i++) {
            int ty = ty0 + i * 8;
            CtH[(size_t)z * 65536 + (size_t)(c0 + ty) * 256 + r0 + tx] = f2h(tile[tx][ty]);
        }
    } else {
        const int r0 = (z - 64) * 256 + blockIdx.y * 32;       // W rows
        const int c0 = blockIdx.x * 32;
#pragma unroll
        for (int i = 0; i < 4; i++) {
            int ty = ty0 + i * 8;
            float v = Wsrc[(size_t)(r0 + ty) * 256 + c0 + tx];
            tile[ty][tx] = v;
            Wp[(size_t)(r0 + ty) * 256 + c0 + tx] = f2h(v);
        }
        __syncthreads();
#pragma unroll
        for (int i = 0; i < 4; i++) {
            int ty = ty0 + i * 8;
            WtH[(size_t)(c0 + ty) * 1024 + r0 + tx] = f2h(tile[tx][ty]);
        }
    }
}

// ---------------------------------------------------------------------------
// G1: M = wc @ WtH^T.  64x64 tile, BK=64, 512 thr (8 waves 2m x 4n, 32x16).
// Depth-2 reg prefetch, dbuf swizzled LDS. Grid 512 (2 blocks/CU).
__global__ __launch_bounds__(512, 4) void k_g1(
    const float* __restrict__ wc, const u16* __restrict__ WtH,
    u16* __restrict__ MH)
{
    __shared__ __align__(16) u16 As[2][64 * 64];
    __shared__ __align__(16) u16 Bs[2][64 * 64];

    const int sbl = xcd_swz((int)blockIdx.x, (int)gridDim.x);
    const int bx = sbl & 3, by = sbl >> 2;
    const int m0 = by * 64, n0 = bx * 64;

    const int t = threadIdx.x;
    const int w = t >> 6, g = (t >> 4) & 3, r = t & 15;
    const int mB = (w >> 2) * 32, nB = (w & 3) * 16;

    float4 fa[2][2];                     // [bank][rowband]
    u32x4 ub[2];                         // [bank]

    auto LOADg = [&](int c, int bk) {
#pragma unroll
        for (int i = 0; i < 2; i++)
            fa[bk][i] = *((const float4*)(wc + (size_t)(m0 + i * 32 + (t >> 4)) * 1024 + c * 64) + (t & 15));
        ub[bk] = *((const u32x4*)(WtH + (size_t)(n0 + (t >> 3)) * 1024 + c * 64) + (t & 7));
    };
    auto STOREg = [&](int bk, int bi) {
        const int grpA = (t & 15) >> 1, half = t & 1;
#pragma unroll
        for (int i = 0; i < 2; i++) {
            const int row = i * 32 + (t >> 4);
            uint2 d = make_uint2(pk2h(fa[bk][i].x, fa[bk][i].y), pk2h(fa[bk][i].z, fa[bk][i].w));
            *(uint2*)&As[bi][row * 64 + ((grpA ^ (row & 7)) << 3) + (half << 2)] = d;
        }
        const int rowB = t >> 3, grpB = t & 7;
        *(u32x4*)&Bs[bi][rowB * 64 + ((grpB ^ (rowB & 7)) << 3)] = ub[bk];
    };

    f32x4 acc[2] = {};
    LOADg(0, 0);
    LOADg(1, 1);
    STOREg(0, 0);
    __syncthreads();

#pragma unroll
    for (int c = 0; c < 16; ++c) {
        if (c + 2 < 16) LOADg(c + 2, c & 1);   // bank of dead chunk c
#pragma unroll
        for (int kh = 0; kh < 2; kh++) {
            f16x8 aF[2], bF;
#pragma unroll
            for (int mi = 0; mi < 2; mi++) {
                const int row = mB + 16 * mi + r;
                aF[mi] = *(const f16x8*)&As[c & 1][row * 64 + ((((kh << 2) | g) ^ (row & 7)) << 3)];
            }
            {
                const int row = nB + r;
                bF = *(const f16x8*)&Bs[c & 1][row * 64 + ((((kh << 2) | g) ^ (row & 7)) << 3)];
            }
#pragma unroll
            for (int mi = 0; mi < 2; mi++)
                acc[mi] = MFMA_F16(aF[mi], bF, acc[mi]);
        }
        if (c + 1 < 16) STOREg((c + 1) & 1, (c + 1) & 1);
        __syncthreads();
    }

#pragma unroll
    for (int mi = 0; mi < 2; mi++)
#pragma unroll
        for (int rr = 0; rr < 4; rr++) {
            const int row = m0 + mB + 16 * mi + 4 * g + rr;
            MH[(size_t)row * 256 + n0 + nB + r] = f2h(acc[mi][rr]);
        }
}

// ---------------------------------------------------------------------------
// MID: per (b, 32-row band): 8-chunk stream (CtH 0-3, CtP 4-7), depth-2 reg
// prefetch; softmax + out2 inserted after chunk 3. 256 blocks x 512 thr.
__global__ __launch_bounds__(512, 2) void k_mid(
    const u16* __restrict__ MH, const u16* __restrict__ CtH,
    const u16* __restrict__ CtP, u16* __restrict__ YtH,
    float* __restrict__ out2)
{
    __shared__ __align__(16) u16 smA[32 * 256];      // 16 KB (M -> P)
    __shared__ __align__(16) u16 smB[2][256 * 64];   // 64 KB
    __shared__ float red[32][8];

    const int sbl = xcd_swz((int)blockIdx.x, (int)gridDim.x);
    const int b = sbl >> 2;
    const int m0 = (sbl & 3) * 32;
    const int gi0 = b * 128 + m0;
    const int t = threadIdx.x;
    const int w = t >> 6, g = (t >> 4) & 3, r = t & 15;

    // stage MH rows gi0..gi0+31 into smA (swizzled), 2 passes
#pragma unroll
    for (int i = 0; i < 2; i++) {
        const int row = i * 16 + (t >> 5), grp = t & 31;
        u32x4 v = *(const u32x4*)(MH + (size_t)(gi0 + row) * 256 + grp * 8);
        *(u32x4*)&smA[row * 256 + ((grp ^ (row & 7)) << 3)] = v;
    }

    const u16* Bh = CtH + (size_t)b * 65536;
    const u16* Bp = CtP + (size_t)b * 65536;

    u32x4 ub[2][4];                      // [bank][i]
    auto LOADC = [&](int c, int bk) {
        const u16* base = (c < 4) ? (Bh + c * 64) : (Bp + (c - 4) * 64);
        const int row0 = t >> 3, grp = t & 7;
#pragma unroll
        for (int i = 0; i < 4; i++)
            ub[bk][i] = *((const u32x4*)(base + (size_t)(i * 64 + row0) * 256) + grp);
    };
    auto STOREC = [&](int bk, int bi) {
        const int row0 = t >> 3, grp = t & 7;
#pragma unroll
        for (int i = 0; i < 4; i++) {
            const int row = i * 64 + row0;
            *(u32x4*)&smB[bi][row * 64 + ((grp ^ (row & 7)) << 3)] = ub[bk][i];
        }
    };

    f32x4 accL[2][2] = {};
    f32x4 accP[2][2] = {};

    LOADC(0, 0);
    LOADC(1, 1);
    STOREC(0, 0);
    __syncthreads();

#pragma unroll
    for (int c = 0; c < 8; ++c) {
        if (c + 2 < 8) LOADC(c + 2, c & 1);

#pragma unroll
        for (int kh = 0; kh < 2; kh++) {
            const int kc = c & 3;        // compile-time under unroll
            const int grp = kc * 8 + kh * 4 + g;
            f16x8 aF[2], bF[2];
#pragma unroll
            for (int mi = 0; mi < 2; mi++)
                aF[mi] = *(const f16x8*)&smA[(mi * 16 + r) * 256 + ((grp ^ (r & 7)) << 3)];
#pragma unroll
            for (int ni = 0; ni < 2; ni++) {
                const int row = w * 32 + ni * 16 + r;
                bF[ni] = *(const f16x8*)&smB[c & 1][row * 64 + ((((kh << 2) | g) ^ (row & 7)) << 3)];
            }
            if (c < 4) {
#pragma unroll
                for (int mi = 0; mi < 2; mi++)
#pragma unroll
                    for (int ni = 0; ni < 2; ni++)
                        accL[mi][ni] = MFMA_F16(aF[mi], bF[ni], accL[mi][ni]);
            } else {
#pragma unroll
                for (int mi = 0; mi < 2; mi++)
#pragma unroll
                    for (int ni = 0; ni < 2; ni++)
                        accP[mi][ni] = MFMA_F16(aF[mi], bF[ni], accP[mi][ni]);
            }
        }

        if (c == 3) {
            // ---- softmax over 256 cols (8 waves share rows via red[32][8])
            float s_[2][4];
#pragma unroll
            for (int mi = 0; mi < 2; mi++)
#pragma unroll
                for (int rr = 0; rr < 4; rr++) {
                    float mx = fmaxf(accL[mi][0][rr], accL[mi][1][rr]);
#pragma unroll
                    for (int m = 1; m < 16; m <<= 1) mx = fmaxf(mx, __shfl_xor(mx, m));
                    if (r == 0) red[mi * 16 + 4 * g + rr][w] = mx;
                }
            __syncthreads();
#pragma unroll
            for (int mi = 0; mi < 2; mi++)
#pragma unroll
                for (int rr = 0; rr < 4; rr++) {
                    const int lrow = mi * 16 + 4 * g + rr;
                    float gmx = red[lrow][0];
#pragma unroll
                    for (int j = 1; j < 8; j++) gmx = fmaxf(gmx, red[lrow][j]);
                    float s = 0.f;
#pragma unroll
                    for (int ni = 0; ni < 2; ni++) {
                        float e = __expf(accL[mi][ni][rr] - gmx);
                        accL[mi][ni][rr] = e;
                        s += e;
                    }
#pragma unroll
                    for (int m = 1; m < 16; m <<= 1) s += __shfl_xor(s, m);
                    s_[mi][rr] = s;
                }
            __syncthreads();
#pragma unroll
            for (int mi = 0; mi < 2; mi++)
#pragma unroll
                for (int rr = 0; rr < 4; rr++)
                    if (r == 0) red[mi * 16 + 4 * g + rr][w] = s_[mi][rr];
            __syncthreads();
            // normalize + park P into smA (M dead)
#pragma unroll
            for (int mi = 0; mi < 2; mi++)
#pragma unroll
                for (int rr = 0; rr < 4; rr++) {
                    const int lrow = mi * 16 + 4 * g + rr;
                    float sum = red[lrow][0];
#pragma unroll
                    for (int j = 1; j < 8; j++) sum += red[lrow][j];
                    const float inv = 1.f / sum;
#pragma unroll
                    for (int ni = 0; ni < 2; ni++) {
                        const float v = accL[mi][ni][rr] * inv;
                        const int col = w * 32 + ni * 16 + r;
                        smA[lrow * 256 + (((col >> 3) ^ (lrow & 7)) << 3) + (col & 7)] = f2h(v);
                    }
                }
            __syncthreads();
            // out2 = P^T: thread t<256 owns column l, 128 B contiguous f32 run
            if (t < 256) {
                const int l = t;
                float vals[32];
#pragma unroll
                for (int row = 0; row < 32; row++)
                    vals[row] = h2f(smA[row * 256 + (((l >> 3) ^ (row & 7)) << 3) + (l & 7)]);
                float4* dst = (float4*)(out2 + (size_t)b * 32768 + (size_t)l * 128 + m0);
#pragma unroll
                for (int q = 0; q < 8; q++)
                    dst[q] = make_float4(vals[4 * q], vals[4 * q + 1],
                                         vals[4 * q + 2], vals[4 * q + 3]);
            }
        }

        if (c + 1 < 8) STOREC((c + 1) & 1, (c + 1) & 1);
        __syncthreads();
    }

    // ---- Yt epilogue (fp16 global)
#pragma unroll
    for (int mi = 0; mi < 2; mi++)
#pragma unroll
        for (int ni = 0; ni < 2; ni++)
#pragma unroll
            for (int rr = 0; rr < 4; rr++) {
                const int row = gi0 + mi * 16 + 4 * g + rr;
                const int col = w * 32 + ni * 16 + r;
                YtH[(size_t)row * 256 + col] = f2h(accP[mi][ni][rr]);
            }
}

// ---------------------------------------------------------------------------
// OUT1: out1 = Yt @ Wp^T. 128x128 tile, BK=64, 512 thr (8 waves 2m x 4n,
// wave 64x32), depth-2 reg prefetch, dbuf LDS. Grid 512 (2 blocks/CU).
__global__ __launch_bounds__(512, 4) void k_out1(
    const u16* __restrict__ Yt, const u16* __restrict__ Wp,
    float* __restrict__ out1)
{
    __shared__ __align__(16) u16 As[2][128 * 64];
    __shared__ __align__(16) u16 Bs[2][128 * 64];

    const int sbl = xcd_swz((int)blockIdx.x, (int)gridDim.x);
    const int bx = sbl & 7, by = sbl >> 3;
    const int m0 = by * 128, n0 = bx * 128;

    const int t = threadIdx.x;
    const int w = t >> 6, g = (t >> 4) & 3, r = t & 15;
    const int mB = (w >> 2) * 64, nB = (w & 3) * 32;

    u32x4 ua[2][2], ub[2][2];            // [bank][rowband]
    auto LOADg = [&](int c, int bk) {
        const int row0 = t >> 3, grp = t & 7;
#pragma unroll
        for (int i = 0; i < 2; i++) {
            ua[bk][i] = *((const u32x4*)(Yt + (size_t)(m0 + i * 64 + row0) * 256 + c * 64) + grp);
            ub[bk][i] = *((const u32x4*)(Wp + (size_t)(n0 + i * 64 + row0) * 256 + c * 64) + grp);
        }
    };
    auto STOREg = [&](int bk, int bi) {
        const int row0 = t >> 3, grp = t & 7;
#pragma unroll
        for (int i = 0; i < 2; i++) {
            const int row = i * 64 + row0;
            *(u32x4*)&As[bi][row * 64 + ((grp ^ (row & 7)) << 3)] = ua[bk][i];
            *(u32x4*)&Bs[bi][row * 64 + ((grp ^ (row & 7)) << 3)] = ub[bk][i];
        }
    };

    f32x4 acc[4][2] = {};
    LOADg(0, 0);
    LOADg(1, 1);
    STOREg(0, 0);
    __syncthreads();

#pragma unroll
    for (int c = 0; c < 4; ++c) {
        if (c + 2 < 4) LOADg(c + 2, c & 1);
#pragma unroll
        for (int kh = 0; kh < 2; kh++) {
            f16x8 aF[4], bF[2];
#pragma unroll
            for (int mi = 0; mi < 4; mi++) {
                const int row = mB + 16 * mi + r;
                aF[mi] = *(const f16x8*)&As[c & 1][row * 64 + ((((kh << 2) | g) ^ (row & 7)) << 3)];
            }
#pragma unroll
            for (int ni = 0; ni < 2; ni++) {
                const int row = nB + 16 * ni + r;
                bF[ni] = *(const f16x8*)&Bs[c & 1][row * 64 + ((((kh << 2) | g) ^ (row & 7)) << 3)];
            }
#pragma unroll
            for (int mi = 0; mi < 4; mi++)
#pragma unroll
                for (int ni = 0; ni < 2; ni++)
                    acc[mi][ni] = MFMA_F16(aF[mi], bF[ni], acc[mi][ni]);
        }
        if (c + 1 < 4) STOREg((c + 1) & 1, (c + 1) & 1);
        __syncthreads();
    }

#pragma unroll
    for (int mi = 0; mi < 4; mi++)
#pragma unroll
        for (int ni = 0; ni < 2; ni++)
#pragma unroll
            for (int rr = 0; rr < 4; rr++) {
                const int row = m0 + mB + 16 * mi + 4 * g + rr;
                const int col = n0 + nB + 16 * ni + r;
                out1[(size_t)row * 1024 + col] = acc[mi][ni][rr];
            }
}

// ---------------------------------------------------------------------------
extern "C" void kernel_launch(void* const* d_in, const int* in_sizes, int n_in,
                              void* d_out, int out_size, void* d_ws, size_t ws_size,
                              hipStream_t stream) {
    const int B = 64, IDF = 128, CDF = 256, L = 256, S2 = 1024;
    const float* wc  = (const float*)d_in[0];   // [B, IDF, S2]
    const float* ctx = (const float*)d_in[1];   // [B, CDF, L]
    const float* W   = (const float*)d_in[2];   // [S2, CDF]
    float* out1 = (float*)d_out;                          // [B,IDF,S2]
    float* out2 = (float*)d_out + (size_t)B * IDF * S2;   // [B,L,IDF]

    char* ws = (char*)d_ws;
    size_t off = 0;
    auto alloc = [&](size_t bytes) -> char* {
        char* p = ws + off;
        off += (bytes + 255) & ~(size_t)255;
        return p;
    };
    u16* WtH = (u16*)alloc((size_t)CDF * S2 * 2);        // W^T fp16 [256][1024]
    u16* Wp  = (u16*)alloc((size_t)S2 * CDF * 2);        // W   fp16 [1024][256]
    u16* CtH = (u16*)alloc((size_t)B * L * CDF * 2);     // ctx^T fp16 [B][l][c]
    u16* CtP = (u16*)alloc((size_t)B * CDF * L * 2);     // ctx fp16  [B][c][l]
    u16* MH  = (u16*)alloc((size_t)B * IDF * CDF * 2);   // M fp16 [8192][256]
    u16* YtH = (u16*)alloc((size_t)B * IDF * CDF * 2);   // Yt fp16 [8192][256]
    (void)ws_size; // ~26 MB

    k_tcvt_all<<<dim3(8, 8, 68), 256, 0, stream>>>(W, ctx, WtH, Wp, CtH, CtP);
    k_g1<<<512, 512, 0, stream>>>(wc, WtH, MH);
    k_mid<<<256, 512, 0, stream>>>(MH, CtH, CtP, YtH, out2);
    k_out1<<<512, 512, 0, stream>>>(YtH, Wp, out1);
}